// Round 1
// baseline (997.352 us; speedup 1.0000x reference)
//
#include <hip/hip_runtime.h>

typedef unsigned short u16;
typedef unsigned int u32;
typedef float f32x4 __attribute__((ext_vector_type(4)));
typedef short s16x8 __attribute__((ext_vector_type(8)));

#define B_ 8
#define C_ 1024
#define N_ 4096
#define FD_ 128
#define P_ 2048
#define PJ_ 384   // 3*FD projection cols

__device__ __forceinline__ u16 f2bf(float f) {
  u32 u = __float_as_uint(f);
  u32 r = (u + 0x7fffu + ((u >> 16) & 1u)) >> 16;
  return (u16)r;
}

// ============================ prep: fp32 -> bf16 weight/pool conversion =====
__global__ __launch_bounds__(256) void prep_kernel(
    const float* __restrict__ wth, const float* __restrict__ wph,
    const float* __restrict__ wg, const float* __restrict__ wo,
    const float* __restrict__ pool,
    u16* __restrict__ wcat, u16* __restrict__ wo_bf,
    u16* __restrict__ pool_k, u16* __restrict__ pool_v) {
  int idx = blockIdx.x * 256 + threadIdx.x;
  if (idx < 393216) {                       // wcat[384][1024]
    int fj = idx >> 10, c = idx & 1023;
    float v = (fj < 128) ? wth[fj * 1024 + c]
              : (fj < 256 ? wph[(fj - 128) * 1024 + c]
                          : wg[(fj - 256) * 1024 + c]);
    wcat[idx] = f2bf(v);
  } else if (idx < 524288) {                // wo_bf[1024][128]
    int i = idx - 393216;
    wo_bf[i] = f2bf(wo[i]);
  } else if (idx < 786432) {                // pool_k[2048][128] = pool^T
    int i = idx - 524288;
    int p = i >> 7, f = i & 127;
    pool_k[i] = f2bf(pool[f * 2048 + p]);
  } else if (idx < 1048576) {               // pool_v[128][2048] = pool
    int i = idx - 786432;
    pool_v[i] = f2bf(pool[i]);
  }
}

// ============================ proj: proj_t[b][n][fj] = sum_c x[b][c][n]*wcat[fj][c]
// block tile: 64 n x 128 fj, BK=64, 4 waves (each 16n x 128f)
__global__ __launch_bounds__(256) void proj_kernel(
    const float* __restrict__ x, const u16* __restrict__ wcat,
    u16* __restrict__ proj) {
  __shared__ u16 xt[64 * 72];      // [n][c] transposed, pitch 72 (144B, 16B-mult)
  __shared__ float ot[64 * 136];   // epilogue transpose, pitch 136 f32 (544B)
  const int tid = threadIdx.x;
  const int w = tid >> 6, lane = tid & 63, lo = lane & 15, hi = lane >> 4;
  const int b = blockIdx.x >> 6, n0 = (blockIdx.x & 63) * 64;
  const int f0 = blockIdx.y * 128;

  f32x4 acc[8];
#pragma unroll
  for (int i = 0; i < 8; ++i)
#pragma unroll
    for (int j = 0; j < 4; ++j) acc[i][j] = 0.f;

  const float* xb = x + (size_t)b * C_ * N_;
  const int cc = tid >> 2, nb = (tid & 3) << 4;

  for (int c0 = 0; c0 < C_; c0 += 64) {
    const float* src = xb + (size_t)(c0 + cc) * N_ + n0 + nb;
    float4 v0 = *(const float4*)(src);
    float4 v1 = *(const float4*)(src + 4);
    float4 v2 = *(const float4*)(src + 8);
    float4 v3 = *(const float4*)(src + 12);
    float tmp[16] = {v0.x, v0.y, v0.z, v0.w, v1.x, v1.y, v1.z, v1.w,
                     v2.x, v2.y, v2.z, v2.w, v3.x, v3.y, v3.z, v3.w};
    __syncthreads();   // previous iter's frag reads done
#pragma unroll
    for (int i = 0; i < 16; ++i) xt[(nb + i) * 72 + cc] = f2bf(tmp[i]);
    __syncthreads();
#pragma unroll
    for (int ks = 0; ks < 2; ++ks) {
      s16x8 af = *(const s16x8*)(xt + (w * 16 + lo) * 72 + ks * 32 + hi * 8);
#pragma unroll
      for (int ft = 0; ft < 8; ++ft) {
        s16x8 bf = *(const s16x8*)(wcat + (f0 + ft * 16 + lo) * 1024 + c0 + ks * 32 + hi * 8);
        acc[ft] = __builtin_amdgcn_mfma_f32_16x16x32_bf16(af, bf, acc[ft], 0, 0, 0);
      }
    }
  }
  // epilogue: stage f32 tile, write coalesced bf16 rows
  __syncthreads();
#pragma unroll
  for (int ft = 0; ft < 8; ++ft)
#pragma unroll
    for (int j = 0; j < 4; ++j)
      ot[(w * 16 + hi * 4 + j) * 136 + ft * 16 + lo] = acc[ft][j];
  __syncthreads();
  const int row = tid >> 2, fc = (tid & 3) * 32;
  u16* dst = proj + (size_t)(b * N_ + n0 + row) * PJ_ + f0 + fc;
  const float* sp = ot + row * 136 + fc;
#pragma unroll
  for (int k2 = 0; k2 < 4; ++k2) {
    s16x8 vv;
#pragma unroll
    for (int i = 0; i < 8; ++i) vv[i] = (short)f2bf(sp[k2 * 8 + i]);
    *(s16x8*)(dst + k2 * 8) = vv;
  }
}

// ============================ transpose g: proj_t[b][n][256+f] -> gv[b][f][n]
__global__ __launch_bounds__(256) void transpose_g(
    const u16* __restrict__ proj, u16* __restrict__ gv) {
  __shared__ u16 tt[64 * 72];
  const int tid = threadIdx.x;
  const int n0 = blockIdx.x * 64, f0 = blockIdx.y * 64, b = blockIdx.z;
  {
    const int nl = tid >> 2, fc = (tid & 3) * 16;
    const u16* src = proj + (size_t)(b * N_ + n0 + nl) * PJ_ + 256 + f0 + fc;
    *(s16x8*)(tt + nl * 72 + fc) = *(const s16x8*)(src);
    *(s16x8*)(tt + nl * 72 + fc + 8) = *(const s16x8*)(src + 8);
  }
  __syncthreads();
  {
    const int fl_ = tid >> 2, nc = (tid & 3) * 16;
    s16x8 a, bv;
#pragma unroll
    for (int i = 0; i < 8; ++i) a[i] = (short)tt[(nc + i) * 72 + fl_];
#pragma unroll
    for (int i = 0; i < 8; ++i) bv[i] = (short)tt[(nc + 8 + i) * 72 + fl_];
    u16* dst = gv + (size_t)b * FD_ * N_ + (size_t)(f0 + fl_) * N_ + n0 + nc;
    *(s16x8*)dst = a;
    *(s16x8*)(dst + 8) = bv;
  }
}

// ============================ fused attention ==============================
// one KV-tile step: 64 keys. K rows at kptr (pitch kp), V at vptr ([f][m], pitch vp)
__device__ __forceinline__ void attn_step(
    const u16* __restrict__ kptr, const int kp,
    const u16* __restrict__ vptr, const int vp,
    const s16x8 q[4], u16* __restrict__ pl, const int lo, const int hi,
    float m_r[4], float l_r[4], f32x4 o[8]) {
  f32x4 s[4];
#pragma unroll
  for (int t = 0; t < 4; ++t)
#pragma unroll
    for (int j = 0; j < 4; ++j) s[t][j] = 0.f;

#pragma unroll
  for (int t = 0; t < 4; ++t) {
    const u16* kr = kptr + (t * 16 + lo) * kp + hi * 8;
#pragma unroll
    for (int kk = 0; kk < 4; ++kk) {
      s16x8 kf = *(const s16x8*)(kr + kk * 32);
      s[t] = __builtin_amdgcn_mfma_f32_16x16x32_bf16(q[kk], kf, s[t], 0, 0, 0);
    }
  }
  // online softmax over this tile's 64 cols (spread over 4 t-tiles x 16 lanes)
  float al[4];
#pragma unroll
  for (int j = 0; j < 4; ++j) {
    float a = fmaxf(fmaxf(s[0][j], s[1][j]), fmaxf(s[2][j], s[3][j]));
    a = fmaxf(a, __shfl_xor(a, 1));
    a = fmaxf(a, __shfl_xor(a, 2));
    a = fmaxf(a, __shfl_xor(a, 4));
    a = fmaxf(a, __shfl_xor(a, 8));
    float mn = fmaxf(m_r[j], a);
    al[j] = __expf(m_r[j] - mn);
    m_r[j] = mn;
  }
  float rs[4] = {0.f, 0.f, 0.f, 0.f};
#pragma unroll
  for (int t = 0; t < 4; ++t)
#pragma unroll
    for (int j = 0; j < 4; ++j) {
      float p = __expf(s[t][j] - m_r[j]);
      s[t][j] = p;
      rs[j] += p;
    }
#pragma unroll
  for (int j = 0; j < 4; ++j) {
    float r = rs[j];
    r += __shfl_xor(r, 1);
    r += __shfl_xor(r, 2);
    r += __shfl_xor(r, 4);
    r += __shfl_xor(r, 8);
    l_r[j] = l_r[j] * al[j] + r;
  }
#pragma unroll
  for (int ft = 0; ft < 8; ++ft)
#pragma unroll
    for (int j = 0; j < 4; ++j) o[ft][j] *= al[j];
  // P -> LDS ([16 n][64 m], pitch 72) to re-fragment as MFMA A operand
#pragma unroll
  for (int t = 0; t < 4; ++t)
#pragma unroll
    for (int j = 0; j < 4; ++j)
      pl[(hi * 4 + j) * 72 + t * 16 + lo] = f2bf(s[t][j]);
  // PV
#pragma unroll
  for (int ks = 0; ks < 2; ++ks) {
    s16x8 af = *(const s16x8*)(pl + lo * 72 + ks * 32 + hi * 8);
#pragma unroll
    for (int ft = 0; ft < 8; ++ft) {
      s16x8 vf = *(const s16x8*)(vptr + (ft * 16 + lo) * vp + ks * 32 + hi * 8);
      o[ft] = __builtin_amdgcn_mfma_f32_16x16x32_bf16(af, vf, o[ft], 0, 0, 0);
    }
  }
}

__global__ __launch_bounds__(256) void attn_kernel(
    const u16* __restrict__ proj, const u16* __restrict__ pool_k,
    const u16* __restrict__ pool_v, const u16* __restrict__ gv,
    u16* __restrict__ feat) {
  __shared__ u16 p_lds[4 * 16 * 72];
  __shared__ float fl[64 * 132];
  const int tid = threadIdx.x;
  const int w = tid >> 6, lane = tid & 63, lo = lane & 15, hi = lane >> 4;
  const int b = blockIdx.x >> 6, n0 = (blockIdx.x & 63) * 64;

  // Q (theta cols 0..127) into registers
  const u16* qbase = proj + (size_t)(b * N_ + n0 + w * 16 + lo) * PJ_;
  s16x8 q[4];
#pragma unroll
  for (int kk = 0; kk < 4; ++kk) q[kk] = *(const s16x8*)(qbase + kk * 32 + hi * 8);

  u16* pl = p_lds + w * 16 * 72;
  float m_r[4], l_r[4];
  f32x4 o[8];
#pragma unroll
  for (int j = 0; j < 4; ++j) { m_r[j] = -INFINITY; l_r[j] = 0.f; }
#pragma unroll
  for (int ft = 0; ft < 8; ++ft)
#pragma unroll
    for (int j = 0; j < 4; ++j) o[ft][j] = 0.f;

  // phase 1: cross-attention over concept pool (2048 keys)
  for (int pt = 0; pt < 32; ++pt)
    attn_step(pool_k + pt * 64 * FD_, FD_, pool_v + pt * 64, P_, q, pl, lo, hi, m_r, l_r, o);

  float o1[8][4];
#pragma unroll
  for (int j = 0; j < 4; ++j) {
    float inv = 1.f / l_r[j];
#pragma unroll
    for (int ft = 0; ft < 8; ++ft) o1[ft][j] = o[ft][j] * inv;
    m_r[j] = -INFINITY;
    l_r[j] = 0.f;
  }
#pragma unroll
  for (int ft = 0; ft < 8; ++ft)
#pragma unroll
    for (int j = 0; j < 4; ++j) o[ft][j] = 0.f;

  // phase 2: self-attention (4096 keys): K = phi (cols 128..255), V = gv[b][f][m]
  const u16* kbase = proj + (size_t)(b * N_) * PJ_ + 128;
  const u16* vbase = gv + (size_t)b * FD_ * N_;
  for (int mt = 0; mt < 64; ++mt)
    attn_step(kbase + (size_t)(mt * 64) * PJ_, PJ_, vbase + mt * 64, N_, q, pl, lo, hi, m_r, l_r, o);

  // combine + stage to LDS f32, then coalesced bf16 write of feat_t[b][n][f]
#pragma unroll
  for (int j = 0; j < 4; ++j) {
    float inv = 1.f / l_r[j];
#pragma unroll
    for (int ft = 0; ft < 8; ++ft)
      fl[(w * 16 + hi * 4 + j) * 132 + ft * 16 + lo] = o1[ft][j] + o[ft][j] * inv;
  }
  __syncthreads();
  const int row = tid >> 2, fc = (tid & 3) * 32;
  const float* sp = fl + row * 132 + fc;
  u16* dst = feat + (size_t)(b * N_ + n0 + row) * FD_ + fc;
#pragma unroll
  for (int k2 = 0; k2 < 4; ++k2) {
    s16x8 vv;
#pragma unroll
    for (int i = 0; i < 8; ++i) vv[i] = (short)f2bf(sp[k2 * 8 + i]);
    *(s16x8*)(dst + k2 * 8) = vv;
  }
}

// ============================ final: out = gamma * (w_o @ feat) + x =========
__global__ __launch_bounds__(256) void final_kernel(
    const float* __restrict__ x, const u16* __restrict__ wo_bf,
    const u16* __restrict__ feat, const float* __restrict__ gamma,
    float* __restrict__ out) {
  __shared__ float fl[64 * 68];
  const int tid = threadIdx.x;
  const int w = tid >> 6, lane = tid & 63, lo = lane & 15, hi = lane >> 4;
  const int n0 = blockIdx.x * 64, c0 = blockIdx.y * 64, b = blockIdx.z;

  f32x4 acc[4];
#pragma unroll
  for (int i = 0; i < 4; ++i)
#pragma unroll
    for (int j = 0; j < 4; ++j) acc[i][j] = 0.f;

  const u16* arow = wo_bf + (c0 + w * 16 + lo) * FD_ + hi * 8;
  const u16* bbase = feat + (size_t)(b * N_ + n0) * FD_;
#pragma unroll
  for (int kk = 0; kk < 4; ++kk) {
    s16x8 af = *(const s16x8*)(arow + kk * 32);
#pragma unroll
    for (int nt = 0; nt < 4; ++nt) {
      s16x8 bf = *(const s16x8*)(bbase + (nt * 16 + lo) * FD_ + kk * 32 + hi * 8);
      acc[nt] = __builtin_amdgcn_mfma_f32_16x16x32_bf16(af, bf, acc[nt], 0, 0, 0);
    }
  }
#pragma unroll
  for (int nt = 0; nt < 4; ++nt)
#pragma unroll
    for (int j = 0; j < 4; ++j)
      fl[(w * 16 + hi * 4 + j) * 68 + nt * 16 + lo] = acc[nt][j];
  __syncthreads();
  const float gm = gamma[0];
  const int cl = tid >> 2, nc = (tid & 3) * 16;
  const size_t xo = (size_t)b * C_ * N_ + (size_t)(c0 + cl) * N_ + n0 + nc;
  const float* sp = fl + cl * 68 + nc;
#pragma unroll
  for (int k2 = 0; k2 < 4; ++k2) {
    float4 v = *(const float4*)(sp + k2 * 4);
    float4 xi = *(const float4*)(x + xo + k2 * 4);
    float4 r;
    r.x = gm * v.x + xi.x;
    r.y = gm * v.y + xi.y;
    r.z = gm * v.z + xi.z;
    r.w = gm * v.w + xi.w;
    *(float4*)(out + xo + k2 * 4) = r;
  }
}

// ============================ launch =======================================
extern "C" void kernel_launch(void* const* d_in, const int* in_sizes, int n_in,
                              void* d_out, int out_size, void* d_ws, size_t ws_size,
                              hipStream_t stream) {
  const float* x = (const float*)d_in[0];
  const float* wth = (const float*)d_in[1];
  const float* wph = (const float*)d_in[2];
  const float* wg = (const float*)d_in[3];
  const float* wo = (const float*)d_in[4];
  const float* gamma = (const float*)d_in[5];
  const float* pool = (const float*)d_in[6];
  float* out = (float*)d_out;

  char* ws = (char*)d_ws;
  u16* wcat   = (u16*)(ws + 0);          //  384*1024*2 = 786432
  u16* wo_bf  = (u16*)(ws + 786432);     // 1024*128*2  = 262144
  u16* pool_k = (u16*)(ws + 1048576);    // 2048*128*2  = 524288
  u16* pool_v = (u16*)(ws + 1572864);    //  128*2048*2 = 524288
  u16* proj   = (u16*)(ws + 2097152);    // 8*4096*384*2 = 25165824
  u16* gv     = (u16*)(ws + 27262976);   // 8*128*4096*2 = 8388608
  u16* feat   = (u16*)(ws + 35651584);   // 8*4096*128*2 = 8388608

  prep_kernel<<<4096, 256, 0, stream>>>(wth, wph, wg, wo, pool, wcat, wo_bf, pool_k, pool_v);
  proj_kernel<<<dim3(512, 3), 256, 0, stream>>>(x, wcat, proj);
  transpose_g<<<dim3(64, 2, 8), 256, 0, stream>>>(proj, gv);
  attn_kernel<<<512, 256, 0, stream>>>(proj, pool_k, pool_v, gv, feat);
  final_kernel<<<dim3(64, 16, 8), 256, 0, stream>>>(x, wo_bf, feat, gamma, out);
}

// Round 2
// 550.426 us; speedup vs baseline: 1.8120x; 1.8120x over previous
//
#include <hip/hip_runtime.h>

typedef unsigned short u16;
typedef unsigned int u32;
typedef float f32x4 __attribute__((ext_vector_type(4)));
typedef short s16x8 __attribute__((ext_vector_type(8)));

#define B_ 8
#define C_ 1024
#define N_ 4096
#define FD_ 128
#define P_ 2048

__device__ __forceinline__ u16 f2bf(float f) {
  u32 u = __float_as_uint(f);
  u32 r = (u + 0x7fffu + ((u >> 16) & 1u)) >> 16;
  return (u16)r;
}
__device__ __forceinline__ u16 f2bf_rtn(float f) {   // cheap round (P>=0)
  return (u16)((__float_as_uint(f) + 0x8000u) >> 16);
}

#define AS1 __attribute__((address_space(1)))
#define AS3 __attribute__((address_space(3)))
__device__ __forceinline__ void gl16(const void* g, void* l) {
  __builtin_amdgcn_global_load_lds((AS1 const u32*)g, (AS3 u32*)l, 16, 0, 0);
}

// ============================ prep: fp32 -> bf16 weights / pool layouts =====
__global__ __launch_bounds__(256) void prep_kernel(
    const float* __restrict__ wth, const float* __restrict__ wph,
    const float* __restrict__ wg, const float* __restrict__ wo,
    const float* __restrict__ pool,
    u16* __restrict__ wcat, u16* __restrict__ wo_bf,
    u16* __restrict__ pool_k, u16* __restrict__ pool_vt) {
  int idx = blockIdx.x * 256 + threadIdx.x;
  if (idx < 393216) {                       // wcat[384][1024]
    int fj = idx >> 10, c = idx & 1023;
    float v = (fj < 128) ? wth[fj * 1024 + c]
              : (fj < 256 ? wph[(fj - 128) * 1024 + c]
                          : wg[(fj - 256) * 1024 + c]);
    wcat[idx] = f2bf(v);
  } else if (idx < 524288) {                // wo_bf[1024][128]
    int i = idx - 393216;
    wo_bf[i] = f2bf(wo[i]);
  } else if (idx < 786432) {                // pool_k[2048][128] = pool^T
    int i = idx - 524288;
    int p = i >> 7, f = i & 127;
    pool_k[i] = f2bf(pool[f * 2048 + p]);
  } else if (idx < 1048576) {               // pool_vt[32][128][64] tiled
    int i = idx - 786432;
    int pt = i >> 13, rem = i & 8191, f = rem >> 6, m = rem & 63;
    pool_vt[i] = f2bf(pool[f * 2048 + pt * 64 + m]);
  }
}

// ============================ proj: theta/phi/g = wcat[y] @ x ==============
// grid (3, 512): y fastest so the 3 projections share the x tile via L2/L3.
__global__ __launch_bounds__(256) void proj_kernel(
    const float* __restrict__ x, const u16* __restrict__ wcat,
    u16* __restrict__ q_t, u16* __restrict__ k_t, u16* __restrict__ gvt) {
  __shared__ u16 xt[64 * 72];      // [n][c] transposed, pitch 72
  __shared__ float ot[64 * 136];   // epilogue transpose, pitch 136 f32
  const int tid = threadIdx.x;
  const int w = tid >> 6, lane = tid & 63, lo = lane & 15, hi = lane >> 4;
  const int y = blockIdx.x;
  const int b = blockIdx.y >> 6, n0 = (blockIdx.y & 63) * 64;
  const int f0 = y * 128;

  f32x4 acc[8];
#pragma unroll
  for (int i = 0; i < 8; ++i)
#pragma unroll
    for (int j = 0; j < 4; ++j) acc[i][j] = 0.f;

  const float* xb = x + (size_t)b * C_ * N_;
  const int cc = tid >> 2, nb = (tid & 3) << 4;

  for (int c0 = 0; c0 < C_; c0 += 64) {
    const float* src = xb + (size_t)(c0 + cc) * N_ + n0 + nb;
    float4 v0 = *(const float4*)(src);
    float4 v1 = *(const float4*)(src + 4);
    float4 v2 = *(const float4*)(src + 8);
    float4 v3 = *(const float4*)(src + 12);
    float tmp[16] = {v0.x, v0.y, v0.z, v0.w, v1.x, v1.y, v1.z, v1.w,
                     v2.x, v2.y, v2.z, v2.w, v3.x, v3.y, v3.z, v3.w};
    __syncthreads();
#pragma unroll
    for (int i = 0; i < 16; ++i) xt[(nb + i) * 72 + cc] = f2bf(tmp[i]);
    __syncthreads();
#pragma unroll
    for (int ks = 0; ks < 2; ++ks) {
      s16x8 af = *(const s16x8*)(xt + (w * 16 + lo) * 72 + ks * 32 + hi * 8);
#pragma unroll
      for (int ft = 0; ft < 8; ++ft) {
        s16x8 bf = *(const s16x8*)(wcat + (f0 + ft * 16 + lo) * 1024 + c0 + ks * 32 + hi * 8);
        acc[ft] = __builtin_amdgcn_mfma_f32_16x16x32_bf16(af, bf, acc[ft], 0, 0, 0);
      }
    }
  }
  __syncthreads();
#pragma unroll
  for (int ft = 0; ft < 8; ++ft)
#pragma unroll
    for (int j = 0; j < 4; ++j)
      ot[(w * 16 + hi * 4 + j) * 136 + ft * 16 + lo] = acc[ft][j];
  __syncthreads();
  if (y < 2) {
    // row-major [b][n][128] output (theta -> q_t, phi -> k_t)
    u16* arr = (y == 0) ? q_t : k_t;
    const int row = tid >> 2, fc = (tid & 3) * 32;
    u16* dst = arr + (size_t)(b * N_ + n0 + row) * FD_ + fc;
    const float* sp = ot + row * 136 + fc;
#pragma unroll
    for (int k2 = 0; k2 < 4; ++k2) {
      s16x8 vv;
#pragma unroll
      for (int i = 0; i < 8; ++i) vv[i] = (short)f2bf(sp[k2 * 8 + i]);
      *(s16x8*)(dst + k2 * 8) = vv;
    }
  } else {
    // transposed tiled output: gvt[b][mt][f][m], mt = n0/64
    const int f = tid >> 1, mh = (tid & 1) * 32;
    u16* dst = gvt + ((size_t)(b * 64 + (n0 >> 6)) * 128 + f) * 64 + mh;
#pragma unroll
    for (int k2 = 0; k2 < 4; ++k2) {
      s16x8 vv;
#pragma unroll
      for (int i = 0; i < 8; ++i) vv[i] = (short)f2bf(ot[(mh + k2 * 8 + i) * 136 + f]);
      *(s16x8*)(dst + k2 * 8) = vv;
    }
  }
}

// ============================ fused attention ==============================
// 4 waves x 16 queries = 64 q/block, 512 blocks (2 blocks/CU).
// 96 KV tiles of 64 keys: [0,32) pool cross-attn, [32,96) self-attn.
// K/V double-buffered in LDS via global_load_lds, XOR-swizzled (src-side).
__global__ __launch_bounds__(256, 2) void attn_kernel(
    const u16* __restrict__ q_t, const u16* __restrict__ k_t,
    const u16* __restrict__ pool_k, const u16* __restrict__ pool_vt,
    const u16* __restrict__ gvt, u16* __restrict__ feat) {
  __shared__ __align__(16) u16 smem[36864];  // kb[2][8192] | vb[2][8192] | p[4][1024]
  u16* kb = smem;
  u16* vb = smem + 16384;
  float* fl = (float*)smem;                  // epilogue alias (33792B)

  const int tid = threadIdx.x;
  const int w = tid >> 6, lane = tid & 63, lo = lane & 15, hi = lane >> 4;
  const int b = blockIdx.x >> 6, n0 = (blockIdx.x & 63) * 64;
  u16* pl = smem + 32768 + w * 1024;         // [16 q][64 k] swizzled, per wave

  // per-lane staging geometry
  const int k_dr = lane >> 4, k_cb = (lane & 15) * 16;
  const int v_dr = lane >> 3, v_cb = (lane & 7) * 16;

  // Q fragments (16 rows per wave)
  const u16* qbase = q_t + (size_t)(b * N_ + n0 + w * 16 + lo) * FD_;
  s16x8 q[4];
#pragma unroll
  for (int kk = 0; kk < 4; ++kk) q[kk] = *(const s16x8*)(qbase + kk * 32 + hi * 8);

  float m_r[4], l_r[4];
  f32x4 o[8];
  float o1[8][4];
#pragma unroll
  for (int j = 0; j < 4; ++j) { m_r[j] = -__builtin_inff(); l_r[j] = 0.f; }
#pragma unroll
  for (int ft = 0; ft < 8; ++ft)
#pragma unroll
    for (int j = 0; j < 4; ++j) { o[ft][j] = 0.f; o1[ft][j] = 0.f; }

  const u16* ktb = k_t + (size_t)b * N_ * FD_;
  const u16* vtb = gvt + (size_t)b * 64 * 8192;

  // prologue: stage tile 0 into buf 0
  {
    const char* kg = (const char*)pool_k;
    const char* vg = (const char*)pool_vt;
#pragma unroll
    for (int cc2 = 0; cc2 < 4; ++cc2) {
      int c = w * 4 + cc2;
      int rl = c * 4 + k_dr;
      gl16(kg + rl * 256 + (k_cb ^ ((rl & 7) << 4)), (char*)kb + c * 1024);
      int fr = c * 8 + v_dr;
      gl16(vg + fr * 128 + (v_cb ^ ((fr & 7) << 4)), (char*)vb + c * 1024);
    }
  }
  __syncthreads();

  int buf = 0;
  for (int i = 0; i < 96; ++i) {
    // prefetch next tile into buf^1
    if (i + 1 < 96) {
      const char* kg;
      const char* vg;
      if (i + 1 < 32) {
        kg = (const char*)(pool_k + (i + 1) * 8192);
        vg = (const char*)(pool_vt + (i + 1) * 8192);
      } else {
        kg = (const char*)(ktb + (size_t)(i + 1 - 32) * 64 * FD_);
        vg = (const char*)(vtb + (size_t)(i + 1 - 32) * 8192);
      }
      char* kl = (char*)kb + (buf ^ 1) * 16384;
      char* vl = (char*)vb + (buf ^ 1) * 16384;
#pragma unroll
      for (int cc2 = 0; cc2 < 4; ++cc2) {
        int c = w * 4 + cc2;
        int rl = c * 4 + k_dr;
        gl16(kg + rl * 256 + (k_cb ^ ((rl & 7) << 4)), kl + c * 1024);
        int fr = c * 8 + v_dr;
        gl16(vg + fr * 128 + (v_cb ^ ((fr & 7) << 4)), vl + c * 1024);
      }
    }
    // phase boundary: finalize pool attention, reset state
    if (i == 32) {
#pragma unroll
      for (int j = 0; j < 4; ++j) {
        float inv = 1.f / l_r[j];
#pragma unroll
        for (int ft = 0; ft < 8; ++ft) { o1[ft][j] = o[ft][j] * inv; o[ft][j] = 0.f; }
        m_r[j] = -__builtin_inff();
        l_r[j] = 0.f;
      }
    }

    const char* kbc = (const char*)kb + buf * 16384;
    const char* vbc = (const char*)vb + buf * 16384;

    // QK^T
    f32x4 s[4];
#pragma unroll
    for (int t = 0; t < 4; ++t) {
#pragma unroll
      for (int j = 0; j < 4; ++j) s[t][j] = 0.f;
      const int r = t * 16 + lo;
      const char* kr = kbc + r * 256;
      const int sw = (r & 7) << 4;
#pragma unroll
      for (int kk = 0; kk < 4; ++kk) {
        s16x8 kf = *(const s16x8*)(kr + ((kk * 64 + hi * 16) ^ sw));
        s[t] = __builtin_amdgcn_mfma_f32_16x16x32_bf16(q[kk], kf, s[t], 0, 0, 0);
      }
    }
    // online softmax with defer-max (THR=8)
    float tmax[4];
#pragma unroll
    for (int j = 0; j < 4; ++j) {
      float a = fmaxf(fmaxf(s[0][j], s[1][j]), fmaxf(s[2][j], s[3][j]));
      a = fmaxf(a, __shfl_xor(a, 1));
      a = fmaxf(a, __shfl_xor(a, 2));
      a = fmaxf(a, __shfl_xor(a, 4));
      a = fmaxf(a, __shfl_xor(a, 8));
      tmax[j] = a;
    }
    float d = fmaxf(fmaxf(tmax[0] - m_r[0], tmax[1] - m_r[1]),
                    fmaxf(tmax[2] - m_r[2], tmax[3] - m_r[3]));
    if (__any(d > 8.f)) {
#pragma unroll
      for (int j = 0; j < 4; ++j) {
        float mn = fmaxf(m_r[j], tmax[j]);
        float al = __expf(m_r[j] - mn);
        m_r[j] = mn;
        l_r[j] *= al;
#pragma unroll
        for (int ft = 0; ft < 8; ++ft) o[ft][j] *= al;
      }
    }
    float rs[4] = {0.f, 0.f, 0.f, 0.f};
#pragma unroll
    for (int t = 0; t < 4; ++t)
#pragma unroll
      for (int j = 0; j < 4; ++j) {
        float p = __expf(s[t][j] - m_r[j]);
        s[t][j] = p;
        rs[j] += p;
      }
#pragma unroll
    for (int j = 0; j < 4; ++j) {
      float r = rs[j];
      r += __shfl_xor(r, 1);
      r += __shfl_xor(r, 2);
      r += __shfl_xor(r, 4);
      r += __shfl_xor(r, 8);
      l_r[j] += r;
    }
    // P -> LDS (swizzled pitch-64 rows)
    char* plw = (char*)pl;
#pragma unroll
    for (int t = 0; t < 4; ++t)
#pragma unroll
      for (int j = 0; j < 4; ++j) {
        int qr = hi * 4 + j;
        *(u16*)(plw + qr * 128 + (((t * 16 + lo) * 2) ^ ((qr & 7) << 4))) =
            f2bf_rtn(s[t][j]);
      }
    // PV
    const char* plr = (const char*)pl + lo * 128;
    const int psw = (lo & 7) << 4;
#pragma unroll
    for (int ks = 0; ks < 2; ++ks) {
      s16x8 af = *(const s16x8*)(plr + ((ks * 64 + hi * 16) ^ psw));
#pragma unroll
      for (int ft = 0; ft < 8; ++ft) {
        const int f = ft * 16 + lo;
        s16x8 vf = *(const s16x8*)(vbc + f * 128 + ((ks * 64 + hi * 16) ^ ((f & 7) << 4)));
        o[ft] = __builtin_amdgcn_mfma_f32_16x16x32_bf16(af, vf, o[ft], 0, 0, 0);
      }
    }
    __syncthreads();   // drains prefetch (vmcnt) + protects buf swap
    buf ^= 1;
  }

  // epilogue: combine pool + SA, stage f32, coalesced bf16 write
#pragma unroll
  for (int j = 0; j < 4; ++j) {
    float inv = 1.f / l_r[j];
#pragma unroll
    for (int ft = 0; ft < 8; ++ft)
      fl[(w * 16 + hi * 4 + j) * 132 + ft * 16 + lo] = o1[ft][j] + o[ft][j] * inv;
  }
  __syncthreads();
  const int row = tid >> 2, fc = (tid & 3) * 32;
  const float* sp = fl + row * 132 + fc;
  u16* dst = feat + (size_t)(b * N_ + n0 + row) * FD_ + fc;
#pragma unroll
  for (int k2 = 0; k2 < 4; ++k2) {
    s16x8 vv;
#pragma unroll
    for (int i = 0; i < 8; ++i) vv[i] = (short)f2bf(sp[k2 * 8 + i]);
    *(s16x8*)(dst + k2 * 8) = vv;
  }
}

// ============================ final: out = gamma * (w_o @ feat) + x =========
__global__ __launch_bounds__(256) void final_kernel(
    const float* __restrict__ x, const u16* __restrict__ wo_bf,
    const u16* __restrict__ feat, const float* __restrict__ gamma,
    float* __restrict__ out) {
  __shared__ float fl[64 * 68];
  const int tid = threadIdx.x;
  const int w = tid >> 6, lane = tid & 63, lo = lane & 15, hi = lane >> 4;
  const int n0 = blockIdx.x * 64, c0 = blockIdx.y * 64, b = blockIdx.z;

  f32x4 acc[4];
#pragma unroll
  for (int i = 0; i < 4; ++i)
#pragma unroll
    for (int j = 0; j < 4; ++j) acc[i][j] = 0.f;

  const u16* arow = wo_bf + (c0 + w * 16 + lo) * FD_ + hi * 8;
  const u16* bbase = feat + (size_t)(b * N_ + n0) * FD_;
#pragma unroll
  for (int kk = 0; kk < 4; ++kk) {
    s16x8 af = *(const s16x8*)(arow + kk * 32);
#pragma unroll
    for (int nt = 0; nt < 4; ++nt) {
      s16x8 bf = *(const s16x8*)(bbase + (nt * 16 + lo) * FD_ + kk * 32 + hi * 8);
      acc[nt] = __builtin_amdgcn_mfma_f32_16x16x32_bf16(af, bf, acc[nt], 0, 0, 0);
    }
  }
#pragma unroll
  for (int nt = 0; nt < 4; ++nt)
#pragma unroll
    for (int j = 0; j < 4; ++j)
      fl[(w * 16 + hi * 4 + j) * 68 + nt * 16 + lo] = acc[nt][j];
  __syncthreads();
  const float gm = gamma[0];
  const int cl = tid >> 2, nc = (tid & 3) * 16;
  const size_t xo = (size_t)b * C_ * N_ + (size_t)(c0 + cl) * N_ + n0 + nc;
  const float* sp = fl + cl * 68 + nc;
#pragma unroll
  for (int k2 = 0; k2 < 4; ++k2) {
    float4 v = *(const float4*)(sp + k2 * 4);
    float4 xi = *(const float4*)(x + xo + k2 * 4);
    float4 r;
    r.x = gm * v.x + xi.x;
    r.y = gm * v.y + xi.y;
    r.z = gm * v.z + xi.z;
    r.w = gm * v.w + xi.w;
    *(float4*)(out + xo + k2 * 4) = r;
  }
}

// ============================ launch =======================================
extern "C" void kernel_launch(void* const* d_in, const int* in_sizes, int n_in,
                              void* d_out, int out_size, void* d_ws, size_t ws_size,
                              hipStream_t stream) {
  const float* x = (const float*)d_in[0];
  const float* wth = (const float*)d_in[1];
  const float* wph = (const float*)d_in[2];
  const float* wg = (const float*)d_in[3];
  const float* wo = (const float*)d_in[4];
  const float* gamma = (const float*)d_in[5];
  const float* pool = (const float*)d_in[6];
  float* out = (float*)d_out;

  char* ws = (char*)d_ws;
  u16* wcat    = (u16*)(ws + 0);          //  384*1024*2 = 786432
  u16* wo_bf   = (u16*)(ws + 786432);     // 1024*128*2  = 262144
  u16* pool_k  = (u16*)(ws + 1048576);    // 2048*128*2  = 524288
  u16* pool_vt = (u16*)(ws + 1572864);    //  32*128*64*2 = 524288
  u16* q_t     = (u16*)(ws + 2097152);    // 8*4096*128*2 = 8388608
  u16* k_t     = (u16*)(ws + 10485760);   // 8*4096*128*2 = 8388608
  u16* gvt     = (u16*)(ws + 18874368);   // 8*64*128*64*2 = 8388608
  u16* feat    = (u16*)(ws + 27262976);   // 8*4096*128*2 = 8388608

  prep_kernel<<<4096, 256, 0, stream>>>(wth, wph, wg, wo, pool, wcat, wo_bf, pool_k, pool_vt);
  proj_kernel<<<dim3(3, 512), 256, 0, stream>>>(x, wcat, q_t, k_t, gvt);
  attn_kernel<<<512, 256, 0, stream>>>(q_t, k_t, pool_k, pool_vt, gvt, feat);
  final_kernel<<<dim3(64, 16, 8), 256, 0, stream>>>(x, wo_bf, feat, gamma, out);
}

// Round 3
// 533.571 us; speedup vs baseline: 1.8692x; 1.0316x over previous
//
#include <hip/hip_runtime.h>

typedef unsigned short u16;
typedef unsigned int u32;
typedef float f32x4 __attribute__((ext_vector_type(4)));
typedef short s16x8 __attribute__((ext_vector_type(8)));

#define B_ 8
#define C_ 1024
#define N_ 4096
#define FD_ 128
#define P_ 2048
#define LOG2E 1.4426950408889634f

__device__ __forceinline__ u16 f2bf(float f) {
  u32 u = __float_as_uint(f);
  u32 r = (u + 0x7fffu + ((u >> 16) & 1u)) >> 16;
  return (u16)r;
}
__device__ __forceinline__ u32 pkbf(float a, float b) {  // {lo:bf16(a), hi:bf16(b)}
  u32 r;
  asm("v_cvt_pk_bf16_f32 %0, %1, %2" : "=v"(r) : "v"(a), "v"(b));
  return r;
}
__device__ __forceinline__ float lo16(u32 u) { return __uint_as_float(u << 16); }
__device__ __forceinline__ float hi16(u32 u) { return __uint_as_float(u & 0xffff0000u); }

#define AS1 __attribute__((address_space(1)))
#define AS3 __attribute__((address_space(3)))
__device__ __forceinline__ void gl16(const void* g, void* l) {
  __builtin_amdgcn_global_load_lds((AS1 const u32*)g, (AS3 u32*)l, 16, 0, 0);
}

// ============================ prep: fp32 -> bf16 weights / pool layouts =====
__global__ __launch_bounds__(256) void prep_kernel(
    const float* __restrict__ wth, const float* __restrict__ wph,
    const float* __restrict__ wg, const float* __restrict__ wo,
    const float* __restrict__ pool,
    u16* __restrict__ wcat, u16* __restrict__ wo_bf,
    u16* __restrict__ pool_k, u16* __restrict__ pool_vt) {
  int idx = blockIdx.x * 256 + threadIdx.x;
  if (idx < 393216) {                       // wcat[384][1024]
    int fj = idx >> 10, c = idx & 1023;
    float v = (fj < 128) ? wth[fj * 1024 + c]
              : (fj < 256 ? wph[(fj - 128) * 1024 + c]
                          : wg[(fj - 256) * 1024 + c]);
    wcat[idx] = f2bf(v);
  } else if (idx < 524288) {                // wo_bf[1024][128]
    int i = idx - 393216;
    wo_bf[i] = f2bf(wo[i]);
  } else if (idx < 786432) {                // pool_k[2048][128] = pool^T
    int i = idx - 524288;
    int p = i >> 7, f = i & 127;
    pool_k[i] = f2bf(pool[f * 2048 + p]);
  } else if (idx < 1048576) {               // pool_vt[32][128][64] tiled V^T
    int i = idx - 786432;
    int pt = i >> 13, rem = i & 8191, f = rem >> 6, m = rem & 63;
    pool_vt[i] = f2bf(pool[f * 2048 + pt * 64 + m]);
  }
}

// ============================ proj: all 3 projections per block =============
// block: 64 n x 384 f. theta scaled by LOG2E (exp2 softmax downstream).
__global__ __launch_bounds__(256, 3) void proj_kernel(
    const float* __restrict__ x, const u16* __restrict__ wcat,
    u16* __restrict__ q_t, u16* __restrict__ k_t, u16* __restrict__ gvt) {
  __shared__ u16 xt[64 * 72];      // [n][c] transposed, pitch 72
  __shared__ float ot[64 * 136];   // epilogue transpose, pitch 136 f32
  const int tid = threadIdx.x;
  const int w = tid >> 6, lane = tid & 63, lo = lane & 15, hi = lane >> 4;
  const int b = blockIdx.x >> 6, n0 = (blockIdx.x & 63) * 64;

  f32x4 acc[3][8];
#pragma unroll
  for (int y = 0; y < 3; ++y)
#pragma unroll
    for (int i = 0; i < 8; ++i)
#pragma unroll
      for (int j = 0; j < 4; ++j) acc[y][i][j] = 0.f;

  const float* xb = x + (size_t)b * C_ * N_;
  const int cc = tid >> 2, nb = (tid & 3) << 4;

  for (int c0 = 0; c0 < C_; c0 += 64) {
    const float* src = xb + (size_t)(c0 + cc) * N_ + n0 + nb;
    float4 v0 = *(const float4*)(src);
    float4 v1 = *(const float4*)(src + 4);
    float4 v2 = *(const float4*)(src + 8);
    float4 v3 = *(const float4*)(src + 12);
    float tmp[16] = {v0.x, v0.y, v0.z, v0.w, v1.x, v1.y, v1.z, v1.w,
                     v2.x, v2.y, v2.z, v2.w, v3.x, v3.y, v3.z, v3.w};
    __syncthreads();
#pragma unroll
    for (int i = 0; i < 16; ++i) xt[(nb + i) * 72 + cc] = f2bf(tmp[i]);
    __syncthreads();
#pragma unroll
    for (int y = 0; y < 3; ++y)
#pragma unroll
      for (int ks = 0; ks < 2; ++ks) {
        s16x8 af = *(const s16x8*)(xt + (w * 16 + lo) * 72 + ks * 32 + hi * 8);
#pragma unroll
        for (int ft = 0; ft < 8; ++ft) {
          s16x8 bf = *(const s16x8*)(wcat + (y * 128 + ft * 16 + lo) * 1024 + c0 + ks * 32 + hi * 8);
          acc[y][ft] = __builtin_amdgcn_mfma_f32_16x16x32_bf16(af, bf, acc[y][ft], 0, 0, 0);
        }
      }
  }
#pragma unroll
  for (int y = 0; y < 3; ++y) {
    const float sc = (y == 0) ? LOG2E : 1.f;
    __syncthreads();
#pragma unroll
    for (int ft = 0; ft < 8; ++ft)
#pragma unroll
      for (int j = 0; j < 4; ++j)
        ot[(w * 16 + hi * 4 + j) * 136 + ft * 16 + lo] = acc[y][ft][j] * sc;
    __syncthreads();
    if (y < 2) {
      u16* arr = (y == 0) ? q_t : k_t;
      const int row = tid >> 2, fc = (tid & 3) * 32;
      u16* dst = arr + (size_t)(b * N_ + n0 + row) * FD_ + fc;
      const float* sp = ot + row * 136 + fc;
#pragma unroll
      for (int k2 = 0; k2 < 4; ++k2) {
        s16x8 vv;
#pragma unroll
        for (int i = 0; i < 8; ++i) vv[i] = (short)f2bf(sp[k2 * 8 + i]);
        *(s16x8*)(dst + k2 * 8) = vv;
      }
    } else {
      const int f = tid >> 1, mh = (tid & 1) * 32;
      u16* dst = gvt + ((size_t)(b * 64 + (n0 >> 6)) * 128 + f) * 64 + mh;
#pragma unroll
      for (int k2 = 0; k2 < 4; ++k2) {
        s16x8 vv;
#pragma unroll
        for (int i = 0; i < 8; ++i) vv[i] = (short)f2bf(ot[(mh + k2 * 8 + i) * 136 + f]);
        *(s16x8*)(dst + k2 * 8) = vv;
      }
    }
  }
}

// ============================ fused attention (swapped-operand) ============
// b = blockIdx&7 -> one batch per XCD (L2-resident KV). 64 q/block.
// S^T = mfma(K, Q): lane owns q = lane&15; softmax in-register, scalar m/l.
__global__ __launch_bounds__(256, 2) void attn_kernel(
    const u16* __restrict__ q_t, const u16* __restrict__ k_t,
    const u16* __restrict__ pool_k, const u16* __restrict__ pool_vt,
    const u16* __restrict__ gvt, u16* __restrict__ feat) {
  __shared__ __align__(16) char smem[65536];   // K dbuf 32K | V dbuf 32K
  char* kB = smem;
  char* vB = smem + 32768;
  float* fl = (float*)smem;                    // epilogue alias (33792B)

  const int tid = threadIdx.x;
  const int w = tid >> 6, lane = tid & 63, lo = lane & 15, hi = lane >> 4;
  const int b = blockIdx.x & 7, n0 = (blockIdx.x >> 3) * 64;

  const int k_dr = lane >> 4, k_cb = (lane & 15) * 16;
  const int v_dr = lane >> 3, v_cb = (lane & 7) * 16;
  const int sw = (lo & 7) << 4;                // read-side swizzle (row&7 == lo&7)
  const int hiT = hi >> 1;
  const int srcA = lo + 32 * (hi & 1), srcB = srcA + 16;

  // Q fragments (already scaled by LOG2E)
  const u16* qbase = q_t + (size_t)(b * N_ + n0 + w * 16 + lo) * FD_;
  s16x8 q0 = *(const s16x8*)(qbase);
  s16x8 q1 = *(const s16x8*)(qbase + 32 + hi * 8 - hi * 8 + 32);  // placeholder fix below
  // (load properly)
  q0 = *(const s16x8*)(qbase + 0 * 32 + hi * 8);
  q1 = *(const s16x8*)(qbase + 1 * 32 + hi * 8);
  s16x8 q2 = *(const s16x8*)(qbase + 2 * 32 + hi * 8);
  s16x8 q3 = *(const s16x8*)(qbase + 3 * 32 + hi * 8);

  float m_r = -__builtin_inff(), l_r = 0.f;
  f32x4 o[8];
  u32 o1p[8][2];
#pragma unroll
  for (int ft = 0; ft < 8; ++ft) {
#pragma unroll
    for (int j = 0; j < 4; ++j) o[ft][j] = 0.f;
    o1p[ft][0] = 0u;
    o1p[ft][1] = 0u;
  }

  const u16* ktb = k_t + (size_t)b * N_ * FD_;
  const u16* vtb = gvt + (size_t)b * 64 * 8192;

  // prologue: stage tile 0 into buf 0
  {
    const char* kg = (const char*)pool_k;
    const char* vg = (const char*)pool_vt;
#pragma unroll
    for (int cc2 = 0; cc2 < 4; ++cc2) {
      int c = w * 4 + cc2;
      int rl = c * 4 + k_dr;
      gl16(kg + rl * 256 + (k_cb ^ ((rl & 7) << 4)), kB + c * 1024);
      int fr = c * 8 + v_dr;
      gl16(vg + fr * 128 + (v_cb ^ ((fr & 7) << 4)), vB + c * 1024);
    }
  }
  __syncthreads();

  int buf = 0;
  for (int i = 0; i < 96; ++i) {
    if (i + 1 < 96) {
      const char* kg;
      const char* vg;
      if (i + 1 < 32) {
        kg = (const char*)(pool_k + (i + 1) * 8192);
        vg = (const char*)(pool_vt + (i + 1) * 8192);
      } else {
        kg = (const char*)(ktb + (size_t)(i + 1 - 32) * 8192);
        vg = (const char*)(vtb + (size_t)(i + 1 - 32) * 8192);
      }
      char* kl = kB + (buf ^ 1) * 16384;
      char* vl = vB + (buf ^ 1) * 16384;
#pragma unroll
      for (int cc2 = 0; cc2 < 4; ++cc2) {
        int c = w * 4 + cc2;
        int rl = c * 4 + k_dr;
        gl16(kg + rl * 256 + (k_cb ^ ((rl & 7) << 4)), kl + c * 1024);
        int fr = c * 8 + v_dr;
        gl16(vg + fr * 128 + (v_cb ^ ((fr & 7) << 4)), vl + c * 1024);
      }
    }
    if (i == 32) {   // finalize pool phase
      float inv = __builtin_amdgcn_rcpf(l_r);
#pragma unroll
      for (int ft = 0; ft < 8; ++ft) {
        o1p[ft][0] = pkbf(o[ft][0] * inv, o[ft][1] * inv);
        o1p[ft][1] = pkbf(o[ft][2] * inv, o[ft][3] * inv);
#pragma unroll
        for (int j = 0; j < 4; ++j) o[ft][j] = 0.f;
      }
      m_r = -__builtin_inff();
      l_r = 0.f;
    }

    const char* kbc = kB + buf * 16384;
    const char* vbc = vB + buf * 16384;

    // S^T = mfma(K, Q): s[t] row k = t*16+hi*4+r, col q = lo
    f32x4 s0, s1, s2, s3;
#pragma unroll
    for (int j = 0; j < 4; ++j) { s0[j] = 0.f; s1[j] = 0.f; s2[j] = 0.f; s3[j] = 0.f; }
#pragma unroll
    for (int kk = 0; kk < 4; ++kk) {
      const int cb = (kk * 64 + hi * 16) ^ sw;
      s16x8 qk = (kk == 0) ? q0 : (kk == 1) ? q1 : (kk == 2) ? q2 : q3;
      s16x8 kf0 = *(const s16x8*)(kbc + (0 * 16 + lo) * 256 + cb);
      s16x8 kf1 = *(const s16x8*)(kbc + (1 * 16 + lo) * 256 + cb);
      s16x8 kf2 = *(const s16x8*)(kbc + (2 * 16 + lo) * 256 + cb);
      s16x8 kf3 = *(const s16x8*)(kbc + (3 * 16 + lo) * 256 + cb);
      s0 = __builtin_amdgcn_mfma_f32_16x16x32_bf16(kf0, qk, s0, 0, 0, 0);
      s1 = __builtin_amdgcn_mfma_f32_16x16x32_bf16(kf1, qk, s1, 0, 0, 0);
      s2 = __builtin_amdgcn_mfma_f32_16x16x32_bf16(kf2, qk, s2, 0, 0, 0);
      s3 = __builtin_amdgcn_mfma_f32_16x16x32_bf16(kf3, qk, s3, 0, 0, 0);
    }
    // tile max (16 in-reg + 2 shfl)
    float t0 = fmaxf(fmaxf(s0[0], s0[1]), fmaxf(s0[2], s0[3]));
    float t1 = fmaxf(fmaxf(s1[0], s1[1]), fmaxf(s1[2], s1[3]));
    float t2 = fmaxf(fmaxf(s2[0], s2[1]), fmaxf(s2[2], s2[3]));
    float t3 = fmaxf(fmaxf(s3[0], s3[1]), fmaxf(s3[2], s3[3]));
    float tm = fmaxf(fmaxf(t0, t1), fmaxf(t2, t3));
    tm = fmaxf(tm, __shfl_xor(tm, 16));
    tm = fmaxf(tm, __shfl_xor(tm, 32));
    // defer-max rescale (log2 units, THR=11.5)
    if (__any(tm - m_r > 11.5f)) {
      float mn = fmaxf(m_r, tm);
      float al = exp2f(m_r - mn);
      m_r = mn;
      l_r *= al;
#pragma unroll
      for (int ft = 0; ft < 8; ++ft)
#pragma unroll
        for (int j = 0; j < 4; ++j) o[ft][j] *= al;
    }
    // P = exp2(S - m), row-sum
    f32x4 p0, p1, p2, p3;
#pragma unroll
    for (int j = 0; j < 4; ++j) {
      p0[j] = exp2f(s0[j] - m_r);
      p1[j] = exp2f(s1[j] - m_r);
      p2[j] = exp2f(s2[j] - m_r);
      p3[j] = exp2f(s3[j] - m_r);
    }
    float rs = (p0[0] + p0[1]) + (p0[2] + p0[3]);
    rs += (p1[0] + p1[1]) + (p1[2] + p1[3]);
    rs += (p2[0] + p2[1]) + (p2[2] + p2[3]);
    rs += (p3[0] + p3[1]) + (p3[2] + p3[3]);
    rs += __shfl_xor(rs, 16);
    rs += __shfl_xor(rs, 32);
    l_r += rs;
    // pack to bf16 pairs: w[t][c] holds k = t*16+hi*4+2c,+1 for q=lo
    u32 w00 = pkbf(p0[0], p0[1]), w01 = pkbf(p0[2], p0[3]);
    u32 w10 = pkbf(p1[0], p1[1]), w11 = pkbf(p1[2], p1[3]);
    u32 w20 = pkbf(p2[0], p2[1]), w21 = pkbf(p2[2], p2[3]);
    u32 w30 = pkbf(p3[0], p3[1]), w31 = pkbf(p3[2], p3[3]);
    // exchange -> B-frags P^T[k][q]: B[kc][s] = w[2kc+hiT][s&1] from lane srcA/srcB
    union Frag { u32 u[4]; s16x8 v; };
    Frag pb0, pb1;
    {
      u32 a0 = (u32)__shfl((int)w00, srcA), b0 = (u32)__shfl((int)w10, srcA);
      u32 a1 = (u32)__shfl((int)w01, srcA), b1 = (u32)__shfl((int)w11, srcA);
      u32 a2 = (u32)__shfl((int)w00, srcB), b2 = (u32)__shfl((int)w10, srcB);
      u32 a3 = (u32)__shfl((int)w01, srcB), b3 = (u32)__shfl((int)w11, srcB);
      pb0.u[0] = hiT ? b0 : a0;
      pb0.u[1] = hiT ? b1 : a1;
      pb0.u[2] = hiT ? b2 : a2;
      pb0.u[3] = hiT ? b3 : a3;
      u32 c0_ = (u32)__shfl((int)w20, srcA), d0 = (u32)__shfl((int)w30, srcA);
      u32 c1_ = (u32)__shfl((int)w21, srcA), d1 = (u32)__shfl((int)w31, srcA);
      u32 c2_ = (u32)__shfl((int)w20, srcB), d2 = (u32)__shfl((int)w30, srcB);
      u32 c3_ = (u32)__shfl((int)w21, srcB), d3 = (u32)__shfl((int)w31, srcB);
      pb1.u[0] = hiT ? d0 : c0_;
      pb1.u[1] = hiT ? d1 : c1_;
      pb1.u[2] = hiT ? d2 : c2_;
      pb1.u[3] = hiT ? d3 : c3_;
    }
    // PV^T = mfma(V^T, P^T): o[ft] row f = ft*16+hi*4+r, col q = lo
#pragma unroll
    for (int ft = 0; ft < 8; ++ft) {
      const int f = ft * 16 + lo;
      s16x8 vf0 = *(const s16x8*)(vbc + f * 128 + ((0 * 64 + hi * 16) ^ sw));
      s16x8 vf1 = *(const s16x8*)(vbc + f * 128 + ((1 * 64 + hi * 16) ^ sw));
      o[ft] = __builtin_amdgcn_mfma_f32_16x16x32_bf16(vf0, pb0.v, o[ft], 0, 0, 0);
      o[ft] = __builtin_amdgcn_mfma_f32_16x16x32_bf16(vf1, pb1.v, o[ft], 0, 0, 0);
    }
    __syncthreads();   // drains prefetch + protects buf swap
    buf ^= 1;
  }

  // epilogue: feat[n][f] = pool_out + sa_out
  {
    float inv = __builtin_amdgcn_rcpf(l_r);
    const int qr = w * 16 + lo;
#pragma unroll
    for (int ft = 0; ft < 8; ++ft) {
      fl[qr * 132 + ft * 16 + hi * 4 + 0] = lo16(o1p[ft][0]) + o[ft][0] * inv;
      fl[qr * 132 + ft * 16 + hi * 4 + 1] = hi16(o1p[ft][0]) + o[ft][1] * inv;
      fl[qr * 132 + ft * 16 + hi * 4 + 2] = lo16(o1p[ft][1]) + o[ft][2] * inv;
      fl[qr * 132 + ft * 16 + hi * 4 + 3] = hi16(o1p[ft][1]) + o[ft][3] * inv;
    }
  }
  __syncthreads();
  const int row = tid >> 2, fc = (tid & 3) * 32;
  const float* sp = fl + row * 132 + fc;
  u16* dst = feat + (size_t)(b * N_ + n0 + row) * FD_ + fc;
#pragma unroll
  for (int k2 = 0; k2 < 4; ++k2) {
    s16x8 vv;
#pragma unroll
    for (int i = 0; i < 8; ++i) vv[i] = (short)f2bf(sp[k2 * 8 + i]);
    *(s16x8*)(dst + k2 * 8) = vv;
  }
}

// ============================ final: out = gamma * (w_o @ feat) + x =========
__global__ __launch_bounds__(256) void final_kernel(
    const float* __restrict__ x, const u16* __restrict__ wo_bf,
    const u16* __restrict__ feat, const float* __restrict__ gamma,
    float* __restrict__ out) {
  __shared__ float fl[64 * 68];
  const int tid = threadIdx.x;
  const int w = tid >> 6, lane = tid & 63, lo = lane & 15, hi = lane >> 4;
  const int n0 = blockIdx.x * 64, c0 = blockIdx.y * 64, b = blockIdx.z;

  f32x4 acc[4];
#pragma unroll
  for (int i = 0; i < 4; ++i)
#pragma unroll
    for (int j = 0; j < 4; ++j) acc[i][j] = 0.f;

  const u16* arow = wo_bf + (c0 + w * 16 + lo) * FD_ + hi * 8;
  const u16* bbase = feat + (size_t)(b * N_ + n0) * FD_;
#pragma unroll
  for (int kk = 0; kk < 4; ++kk) {
    s16x8 af = *(const s16x8*)(arow + kk * 32);
#pragma unroll
    for (int nt = 0; nt < 4; ++nt) {
      s16x8 bf = *(const s16x8*)(bbase + (nt * 16 + lo) * FD_ + kk * 32 + hi * 8);
      acc[nt] = __builtin_amdgcn_mfma_f32_16x16x32_bf16(af, bf, acc[nt], 0, 0, 0);
    }
  }
#pragma unroll
  for (int nt = 0; nt < 4; ++nt)
#pragma unroll
    for (int j = 0; j < 4; ++j)
      fl[(w * 16 + hi * 4 + j) * 68 + nt * 16 + lo] = acc[nt][j];
  __syncthreads();
  const float gm = gamma[0];
  const int cl = tid >> 2, nc = (tid & 3) * 16;
  const size_t xo = (size_t)b * C_ * N_ + (size_t)(c0 + cl) * N_ + n0 + nc;
  const float* sp = fl + cl * 68 + nc;
#pragma unroll
  for (int k2 = 0; k2 < 4; ++k2) {
    float4 v = *(const float4*)(sp + k2 * 4);
    float4 xi = *(const float4*)(x + xo + k2 * 4);
    float4 r;
    r.x = gm * v.x + xi.x;
    r.y = gm * v.y + xi.y;
    r.z = gm * v.z + xi.z;
    r.w = gm * v.w + xi.w;
    *(float4*)(out + xo + k2 * 4) = r;
  }
}

// ============================ launch =======================================
extern "C" void kernel_launch(void* const* d_in, const int* in_sizes, int n_in,
                              void* d_out, int out_size, void* d_ws, size_t ws_size,
                              hipStream_t stream) {
  const float* x = (const float*)d_in[0];
  const float* wth = (const float*)d_in[1];
  const float* wph = (const float*)d_in[2];
  const float* wg = (const float*)d_in[3];
  const float* wo = (const float*)d_in[4];
  const float* gamma = (const float*)d_in[5];
  const float* pool = (const float*)d_in[6];
  float* out = (float*)d_out;

  char* ws = (char*)d_ws;
  u16* wcat    = (u16*)(ws + 0);          //  384*1024*2 = 786432
  u16* wo_bf   = (u16*)(ws + 786432);     // 1024*128*2  = 262144
  u16* pool_k  = (u16*)(ws + 1048576);    // 2048*128*2  = 524288
  u16* pool_vt = (u16*)(ws + 1572864);    //  32*128*64*2 = 524288
  u16* q_t     = (u16*)(ws + 2097152);    // 8*4096*128*2 = 8388608
  u16* k_t     = (u16*)(ws + 10485760);   // 8*4096*128*2 = 8388608
  u16* gvt     = (u16*)(ws + 18874368);   // 8*64*128*64*2 = 8388608
  u16* feat    = (u16*)(ws + 27262976);   // 8*4096*128*2 = 8388608

  prep_kernel<<<4096, 256, 0, stream>>>(wth, wph, wg, wo, pool, wcat, wo_bf, pool_k, pool_vt);
  proj_kernel<<<512, 256, 0, stream>>>(x, wcat, q_t, k_t, gvt);
  attn_kernel<<<512, 256, 0, stream>>>(q_t, k_t, pool_k, pool_vt, gvt, feat);
  final_kernel<<<dim3(64, 16, 8), 256, 0, stream>>>(x, wo_bf, feat, gamma, out);
}

// Round 4
// 445.684 us; speedup vs baseline: 2.2378x; 1.1972x over previous
//
#include <hip/hip_runtime.h>

typedef unsigned short u16;
typedef unsigned int u32;
typedef float f32x4 __attribute__((ext_vector_type(4)));
typedef short s16x8 __attribute__((ext_vector_type(8)));

#define B_ 8
#define C_ 1024
#define N_ 4096
#define FD_ 128
#define P_ 2048
#define LOG2E 1.4426950408889634f

__device__ __forceinline__ u16 f2bf(float f) {
  u32 u = __float_as_uint(f);
  u32 r = (u + 0x7fffu + ((u >> 16) & 1u)) >> 16;
  return (u16)r;
}
__device__ __forceinline__ u32 pkbf(float a, float b) {  // {lo:bf16(a), hi:bf16(b)}
  u32 r;
  asm("v_cvt_pk_bf16_f32 %0, %1, %2" : "=v"(r) : "v"(a), "v"(b));
  return r;
}
__device__ __forceinline__ float lo16(u32 u) { return __uint_as_float(u << 16); }
__device__ __forceinline__ float hi16(u32 u) { return __uint_as_float(u & 0xffff0000u); }

#define AS1 __attribute__((address_space(1)))
#define AS3 __attribute__((address_space(3)))
__device__ __forceinline__ void gl16(const void* g, void* l) {
  __builtin_amdgcn_global_load_lds((AS1 const u32*)g, (AS3 u32*)l, 16, 0, 0);
}

// ============================ prep: fp32 -> bf16 weights / pool layouts =====
__global__ __launch_bounds__(256) void prep_kernel(
    const float* __restrict__ wth, const float* __restrict__ wph,
    const float* __restrict__ wg, const float* __restrict__ wo,
    const float* __restrict__ pool,
    u16* __restrict__ wcat, u16* __restrict__ wo_bf,
    u16* __restrict__ pool_k, u16* __restrict__ pool_vt) {
  int idx = blockIdx.x * 256 + threadIdx.x;
  if (idx < 393216) {                       // wcat[384][1024]
    int fj = idx >> 10, c = idx & 1023;
    float v = (fj < 128) ? wth[fj * 1024 + c]
              : (fj < 256 ? wph[(fj - 128) * 1024 + c]
                          : wg[(fj - 256) * 1024 + c]);
    wcat[idx] = f2bf(v);
  } else if (idx < 524288) {                // wo_bf[1024][128]
    int i = idx - 393216;
    wo_bf[i] = f2bf(wo[i]);
  } else if (idx < 786432) {                // pool_k[2048][128] = pool^T
    int i = idx - 524288;
    int p = i >> 7, f = i & 127;
    pool_k[i] = f2bf(pool[f * 2048 + p]);
  } else if (idx < 1048576) {               // pool_vt[32][128][64] tiled V^T
    int i = idx - 786432;
    int pt = i >> 13, rem = i & 8191, f = rem >> 6, m = rem & 63;
    pool_vt[i] = f2bf(pool[f * 2048 + pt * 64 + m]);
  }
}

// ============================ proj: pipelined GEMM ==========================
// grid (3 y-slices, 256 tiles): block = 128 n x 128 f, 4 waves (32 n each).
// A (x) -> reg -> bf16 -> swizzled LDS dbuf; B (wcat) -> reg dbuf from L2.
__global__ __launch_bounds__(256, 2) void proj_kernel(
    const float* __restrict__ x, const u16* __restrict__ wcat,
    u16* __restrict__ q_t, u16* __restrict__ k_t, u16* __restrict__ gvt) {
  __shared__ __align__(16) char sm[34816];   // A dbuf 2x16K; epilogue ot aliases
  float* ot = (float*)sm;
  const int tid = threadIdx.x;
  const int w = tid >> 6, lane = tid & 63, lo = lane & 15, hi = lane >> 4;
  const int y = blockIdx.x;
  const int b = blockIdx.y >> 5, n0 = (blockIdx.y & 31) * 128;

  const float* xb = x + (size_t)b * (C_ * N_) + n0;
  const u16* wy = wcat + y * 128 * 1024;
  const int cq = tid & 15, nq = tid >> 4;    // staging: thread = 4c x 8n

  f32x4 acc[2][8];
#pragma unroll
  for (int s = 0; s < 2; ++s)
#pragma unroll
    for (int ft = 0; ft < 8; ++ft)
#pragma unroll
      for (int j = 0; j < 4; ++j) acc[s][ft][j] = 0.f;

  float4 xa[8];
  s16x8 bA[8], bB[8];

#define LOADX(c0)                                                        \
  {                                                                      \
    _Pragma("unroll") for (int i = 0; i < 4; ++i) {                      \
      const float* p = xb + (size_t)((c0) + cq * 4 + i) * N_ + nq * 8;   \
      xa[i * 2] = *(const float4*)p;                                     \
      xa[i * 2 + 1] = *(const float4*)(p + 4);                           \
    }                                                                    \
  }
#define STOREA(bufsel)                                                   \
  {                                                                      \
    char* ab = sm + (bufsel)*16384;                                      \
    _Pragma("unroll") for (int j = 0; j < 8; ++j) {                      \
      float v0 = xa[0 + (j >> 2)][j & 3];                                \
      float v1 = xa[2 + (j >> 2)][j & 3];                                \
      float v2 = xa[4 + (j >> 2)][j & 3];                                \
      float v3 = xa[6 + (j >> 2)][j & 3];                                \
      uint2 pk;                                                          \
      pk.x = pkbf(v0, v1);                                               \
      pk.y = pkbf(v2, v3);                                               \
      int r = nq * 8 + j;                                                \
      *(uint2*)(ab + r * 128 + ((cq * 8) ^ ((r & 7) << 4))) = pk;        \
    }                                                                    \
  }
#define LOADB(dst, c0, ks)                                               \
  {                                                                      \
    _Pragma("unroll") for (int ft = 0; ft < 8; ++ft) dst[ft] =           \
        *(const s16x8*)(wy + (ft * 16 + lo) * 1024 + (c0) + (ks)*32 +    \
                        hi * 8);                                         \
  }
#define COMPUTE(bufsel, ks, bf)                                          \
  {                                                                      \
    const char* ab = sm + (bufsel)*16384;                                \
    _Pragma("unroll") for (int s = 0; s < 2; ++s) {                      \
      int r = w * 32 + s * 16 + lo;                                      \
      s16x8 af = *(const s16x8*)(ab + r * 128 +                          \
                                 (((ks)*64 + hi * 16) ^ ((r & 7) << 4)));\
      _Pragma("unroll") for (int ft = 0; ft < 8; ++ft) acc[s][ft] =      \
          __builtin_amdgcn_mfma_f32_16x16x32_bf16(af, bf[ft],            \
                                                  acc[s][ft], 0, 0, 0);  \
    }                                                                    \
  }

  // prologue: tile 0
  LOADX(0);
  LOADB(bA, 0, 0);
  STOREA(0);
  __syncthreads();

  for (int k = 0; k < 16; ++k) {
    const int c0n = (k + 1) * 64;
    if (k < 15) LOADX(c0n);          // issue-early (lands during compute)
    LOADB(bB, k * 64, 1);            // half-step B prefetch
    COMPUTE(k & 1, 0, bA);
    if (k < 15) LOADB(bA, c0n, 0);   // next-step B prefetch
    COMPUTE(k & 1, 1, bB);
    if (k < 15) STOREA((k & 1) ^ 1); // write-late into other buffer
    __syncthreads();
  }

  // epilogue: two 64-row halves through f32 LDS transpose
  const float sc = (y == 0) ? LOG2E : 1.f;
#pragma unroll
  for (int hn = 0; hn < 2; ++hn) {
    if ((w >> 1) == hn) {
#pragma unroll
      for (int s = 0; s < 2; ++s)
#pragma unroll
        for (int ft = 0; ft < 8; ++ft)
#pragma unroll
          for (int j = 0; j < 4; ++j)
            ot[((w & 1) * 32 + s * 16 + hi * 4 + j) * 136 + ft * 16 + lo] =
                acc[s][ft][j] * sc;
    }
    __syncthreads();
    if (y < 2) {
      u16* arr = (y == 0) ? q_t : k_t;
      const int row = tid >> 2, fc = (tid & 3) * 32;
      u16* dst = arr + (size_t)(b * N_ + n0 + hn * 64 + row) * FD_ + fc;
      const float* sp = ot + row * 136 + fc;
#pragma unroll
      for (int k2 = 0; k2 < 4; ++k2) {
        s16x8 vv;
#pragma unroll
        for (int i = 0; i < 8; ++i) vv[i] = (short)f2bf(sp[k2 * 8 + i]);
        *(s16x8*)(dst + k2 * 8) = vv;
      }
    } else {
      const int f = tid >> 1, mh = (tid & 1) * 32;
      u16* dst = gvt + ((size_t)(b * 64 + ((n0 + hn * 64) >> 6)) * 128 + f) * 64 + mh;
#pragma unroll
      for (int k2 = 0; k2 < 4; ++k2) {
        s16x8 vv;
#pragma unroll
        for (int i = 0; i < 8; ++i) vv[i] = (short)f2bf(ot[(mh + k2 * 8 + i) * 136 + f]);
        *(s16x8*)(dst + k2 * 8) = vv;
      }
    }
    __syncthreads();
  }
#undef LOADX
#undef STOREA
#undef LOADB
#undef COMPUTE
}

// ============================ fused attention (swapped-operand) ============
// b = blockIdx&7 -> one batch per XCD (L2-resident KV). 64 q/block.
// S^T = mfma(K, Q): lane owns q = lane&15; softmax in-register, scalar m/l.
__global__ __launch_bounds__(256, 2) void attn_kernel(
    const u16* __restrict__ q_t, const u16* __restrict__ k_t,
    const u16* __restrict__ pool_k, const u16* __restrict__ pool_vt,
    const u16* __restrict__ gvt, u16* __restrict__ feat) {
  __shared__ __align__(16) char smem[65536];   // K dbuf 32K | V dbuf 32K
  char* kB = smem;
  char* vB = smem + 32768;
  float* fl = (float*)smem;                    // epilogue alias (33792B)

  const int tid = threadIdx.x;
  const int w = tid >> 6, lane = tid & 63, lo = lane & 15, hi = lane >> 4;
  const int b = blockIdx.x & 7, n0 = (blockIdx.x >> 3) * 64;

  const int k_dr = lane >> 4, k_cb = (lane & 15) * 16;
  const int v_dr = lane >> 3, v_cb = (lane & 7) * 16;
  const int sw = (lo & 7) << 4;                // read-side swizzle (row&7 == lo&7)
  const int hiT = hi >> 1;
  const int srcA = lo + 32 * (hi & 1), srcB = srcA + 16;

  // Q fragments (already scaled by LOG2E)
  const u16* qbase = q_t + (size_t)(b * N_ + n0 + w * 16 + lo) * FD_;
  s16x8 q0 = *(const s16x8*)(qbase + 0 * 32 + hi * 8);
  s16x8 q1 = *(const s16x8*)(qbase + 1 * 32 + hi * 8);
  s16x8 q2 = *(const s16x8*)(qbase + 2 * 32 + hi * 8);
  s16x8 q3 = *(const s16x8*)(qbase + 3 * 32 + hi * 8);

  float m_r = -__builtin_inff(), l_r = 0.f;
  f32x4 o[8];
  u32 o1p[8][2];
#pragma unroll
  for (int ft = 0; ft < 8; ++ft) {
#pragma unroll
    for (int j = 0; j < 4; ++j) o[ft][j] = 0.f;
    o1p[ft][0] = 0u;
    o1p[ft][1] = 0u;
  }

  const u16* ktb = k_t + (size_t)b * N_ * FD_;
  const u16* vtb = gvt + (size_t)b * 64 * 8192;

  // prologue: stage tile 0 into buf 0
  {
    const char* kg = (const char*)pool_k;
    const char* vg = (const char*)pool_vt;
#pragma unroll
    for (int cc2 = 0; cc2 < 4; ++cc2) {
      int c = w * 4 + cc2;
      int rl = c * 4 + k_dr;
      gl16(kg + rl * 256 + (k_cb ^ ((rl & 7) << 4)), (char*)kB + c * 1024);
      int fr = c * 8 + v_dr;
      gl16(vg + fr * 128 + (v_cb ^ ((fr & 7) << 4)), (char*)vB + c * 1024);
    }
  }
  __syncthreads();

  int buf = 0;
  for (int i = 0; i < 96; ++i) {
    if (i + 1 < 96) {
      const char* kg;
      const char* vg;
      if (i + 1 < 32) {
        kg = (const char*)(pool_k + (i + 1) * 8192);
        vg = (const char*)(pool_vt + (i + 1) * 8192);
      } else {
        kg = (const char*)(ktb + (size_t)(i + 1 - 32) * 8192);
        vg = (const char*)(vtb + (size_t)(i + 1 - 32) * 8192);
      }
      char* kl = kB + (buf ^ 1) * 16384;
      char* vl = vB + (buf ^ 1) * 16384;
#pragma unroll
      for (int cc2 = 0; cc2 < 4; ++cc2) {
        int c = w * 4 + cc2;
        int rl = c * 4 + k_dr;
        gl16(kg + rl * 256 + (k_cb ^ ((rl & 7) << 4)), kl + c * 1024);
        int fr = c * 8 + v_dr;
        gl16(vg + fr * 128 + (v_cb ^ ((fr & 7) << 4)), vl + c * 1024);
      }
    }
    if (i == 32) {   // finalize pool phase
      float inv = __builtin_amdgcn_rcpf(l_r);
#pragma unroll
      for (int ft = 0; ft < 8; ++ft) {
        o1p[ft][0] = pkbf(o[ft][0] * inv, o[ft][1] * inv);
        o1p[ft][1] = pkbf(o[ft][2] * inv, o[ft][3] * inv);
#pragma unroll
        for (int j = 0; j < 4; ++j) o[ft][j] = 0.f;
      }
      m_r = -__builtin_inff();
      l_r = 0.f;
    }

    const char* kbc = kB + buf * 16384;
    const char* vbc = vB + buf * 16384;

    // S^T = mfma(K, Q): s[t] row k = t*16+hi*4+r, col q = lo
    f32x4 s0, s1, s2, s3;
#pragma unroll
    for (int j = 0; j < 4; ++j) { s0[j] = 0.f; s1[j] = 0.f; s2[j] = 0.f; s3[j] = 0.f; }
#pragma unroll
    for (int kk = 0; kk < 4; ++kk) {
      const int cb = (kk * 64 + hi * 16) ^ sw;
      s16x8 qk = (kk == 0) ? q0 : (kk == 1) ? q1 : (kk == 2) ? q2 : q3;
      s16x8 kf0 = *(const s16x8*)(kbc + (0 * 16 + lo) * 256 + cb);
      s16x8 kf1 = *(const s16x8*)(kbc + (1 * 16 + lo) * 256 + cb);
      s16x8 kf2 = *(const s16x8*)(kbc + (2 * 16 + lo) * 256 + cb);
      s16x8 kf3 = *(const s16x8*)(kbc + (3 * 16 + lo) * 256 + cb);
      s0 = __builtin_amdgcn_mfma_f32_16x16x32_bf16(kf0, qk, s0, 0, 0, 0);
      s1 = __builtin_amdgcn_mfma_f32_16x16x32_bf16(kf1, qk, s1, 0, 0, 0);
      s2 = __builtin_amdgcn_mfma_f32_16x16x32_bf16(kf2, qk, s2, 0, 0, 0);
      s3 = __builtin_amdgcn_mfma_f32_16x16x32_bf16(kf3, qk, s3, 0, 0, 0);
    }
    // tile max (16 in-reg + 2 shfl)
    float t0 = fmaxf(fmaxf(s0[0], s0[1]), fmaxf(s0[2], s0[3]));
    float t1 = fmaxf(fmaxf(s1[0], s1[1]), fmaxf(s1[2], s1[3]));
    float t2 = fmaxf(fmaxf(s2[0], s2[1]), fmaxf(s2[2], s2[3]));
    float t3 = fmaxf(fmaxf(s3[0], s3[1]), fmaxf(s3[2], s3[3]));
    float tm = fmaxf(fmaxf(t0, t1), fmaxf(t2, t3));
    tm = fmaxf(tm, __shfl_xor(tm, 16));
    tm = fmaxf(tm, __shfl_xor(tm, 32));
    // defer-max rescale (log2 units, THR=11.5)
    if (__any(tm - m_r > 11.5f)) {
      float mn = fmaxf(m_r, tm);
      float al = exp2f(m_r - mn);
      m_r = mn;
      l_r *= al;
#pragma unroll
      for (int ft = 0; ft < 8; ++ft)
#pragma unroll
        for (int j = 0; j < 4; ++j) o[ft][j] *= al;
    }
    // P = exp2(S - m), row-sum
    f32x4 p0, p1, p2, p3;
#pragma unroll
    for (int j = 0; j < 4; ++j) {
      p0[j] = exp2f(s0[j] - m_r);
      p1[j] = exp2f(s1[j] - m_r);
      p2[j] = exp2f(s2[j] - m_r);
      p3[j] = exp2f(s3[j] - m_r);
    }
    float rs = (p0[0] + p0[1]) + (p0[2] + p0[3]);
    rs += (p1[0] + p1[1]) + (p1[2] + p1[3]);
    rs += (p2[0] + p2[1]) + (p2[2] + p2[3]);
    rs += (p3[0] + p3[1]) + (p3[2] + p3[3]);
    rs += __shfl_xor(rs, 16);
    rs += __shfl_xor(rs, 32);
    l_r += rs;
    // pack to bf16 pairs: w[t][c] holds k = t*16+hi*4+2c,+1 for q=lo
    u32 w00 = pkbf(p0[0], p0[1]), w01 = pkbf(p0[2], p0[3]);
    u32 w10 = pkbf(p1[0], p1[1]), w11 = pkbf(p1[2], p1[3]);
    u32 w20 = pkbf(p2[0], p2[1]), w21 = pkbf(p2[2], p2[3]);
    u32 w30 = pkbf(p3[0], p3[1]), w31 = pkbf(p3[2], p3[3]);
    // exchange -> B-frags P^T[k][q]
    union Frag { u32 u[4]; s16x8 v; };
    Frag pb0, pb1;
    {
      u32 a0 = (u32)__shfl((int)w00, srcA), b0 = (u32)__shfl((int)w10, srcA);
      u32 a1 = (u32)__shfl((int)w01, srcA), b1 = (u32)__shfl((int)w11, srcA);
      u32 a2 = (u32)__shfl((int)w00, srcB), b2 = (u32)__shfl((int)w10, srcB);
      u32 a3 = (u32)__shfl((int)w01, srcB), b3 = (u32)__shfl((int)w11, srcB);
      pb0.u[0] = hiT ? b0 : a0;
      pb0.u[1] = hiT ? b1 : a1;
      pb0.u[2] = hiT ? b2 : a2;
      pb0.u[3] = hiT ? b3 : a3;
      u32 c0_ = (u32)__shfl((int)w20, srcA), d0 = (u32)__shfl((int)w30, srcA);
      u32 c1_ = (u32)__shfl((int)w21, srcA), d1 = (u32)__shfl((int)w31, srcA);
      u32 c2_ = (u32)__shfl((int)w20, srcB), d2 = (u32)__shfl((int)w30, srcB);
      u32 c3_ = (u32)__shfl((int)w21, srcB), d3 = (u32)__shfl((int)w31, srcB);
      pb1.u[0] = hiT ? d0 : c0_;
      pb1.u[1] = hiT ? d1 : c1_;
      pb1.u[2] = hiT ? d2 : c2_;
      pb1.u[3] = hiT ? d3 : c3_;
    }
    // PV^T = mfma(V^T, P^T): o[ft] row f = ft*16+hi*4+r, col q = lo
#pragma unroll
    for (int ft = 0; ft < 8; ++ft) {
      const int f = ft * 16 + lo;
      s16x8 vf0 = *(const s16x8*)(vbc + f * 128 + ((0 * 64 + hi * 16) ^ sw));
      s16x8 vf1 = *(const s16x8*)(vbc + f * 128 + ((1 * 64 + hi * 16) ^ sw));
      o[ft] = __builtin_amdgcn_mfma_f32_16x16x32_bf16(vf0, pb0.v, o[ft], 0, 0, 0);
      o[ft] = __builtin_amdgcn_mfma_f32_16x16x32_bf16(vf1, pb1.v, o[ft], 0, 0, 0);
    }
    __syncthreads();   // drains prefetch + protects buf swap
    buf ^= 1;
  }

  // epilogue: feat[n][f] = pool_out + sa_out
  {
    float inv = __builtin_amdgcn_rcpf(l_r);
    const int qr = w * 16 + lo;
#pragma unroll
    for (int ft = 0; ft < 8; ++ft) {
      fl[qr * 132 + ft * 16 + hi * 4 + 0] = lo16(o1p[ft][0]) + o[ft][0] * inv;
      fl[qr * 132 + ft * 16 + hi * 4 + 1] = hi16(o1p[ft][0]) + o[ft][1] * inv;
      fl[qr * 132 + ft * 16 + hi * 4 + 2] = lo16(o1p[ft][1]) + o[ft][2] * inv;
      fl[qr * 132 + ft * 16 + hi * 4 + 3] = hi16(o1p[ft][1]) + o[ft][3] * inv;
    }
  }
  __syncthreads();
  const int row = tid >> 2, fc = (tid & 3) * 32;
  const float* sp = fl + row * 132 + fc;
  u16* dst = feat + (size_t)(b * N_ + n0 + row) * FD_ + fc;
#pragma unroll
  for (int k2 = 0; k2 < 4; ++k2) {
    s16x8 vv;
#pragma unroll
    for (int i = 0; i < 8; ++i) vv[i] = (short)f2bf(sp[k2 * 8 + i]);
    *(s16x8*)(dst + k2 * 8) = vv;
  }
}

// ============================ final: out = gamma * (w_o @ feat) + x =========
__global__ __launch_bounds__(256) void final_kernel(
    const float* __restrict__ x, const u16* __restrict__ wo_bf,
    const u16* __restrict__ feat, const float* __restrict__ gamma,
    float* __restrict__ out) {
  __shared__ float fl[64 * 68];
  const int tid = threadIdx.x;
  const int w = tid >> 6, lane = tid & 63, lo = lane & 15, hi = lane >> 4;
  const int n0 = blockIdx.x * 64, c0 = blockIdx.y * 64, b = blockIdx.z;

  f32x4 acc[4];
#pragma unroll
  for (int i = 0; i < 4; ++i)
#pragma unroll
    for (int j = 0; j < 4; ++j) acc[i][j] = 0.f;

  const u16* arow = wo_bf + (c0 + w * 16 + lo) * FD_ + hi * 8;
  const u16* bbase = feat + (size_t)(b * N_ + n0) * FD_;
#pragma unroll
  for (int kk = 0; kk < 4; ++kk) {
    s16x8 af = *(const s16x8*)(arow + kk * 32);
#pragma unroll
    for (int nt = 0; nt < 4; ++nt) {
      s16x8 bf = *(const s16x8*)(bbase + (nt * 16 + lo) * FD_ + kk * 32 + hi * 8);
      acc[nt] = __builtin_amdgcn_mfma_f32_16x16x32_bf16(af, bf, acc[nt], 0, 0, 0);
    }
  }
#pragma unroll
  for (int nt = 0; nt < 4; ++nt)
#pragma unroll
    for (int j = 0; j < 4; ++j)
      fl[(w * 16 + hi * 4 + j) * 68 + nt * 16 + lo] = acc[nt][j];
  __syncthreads();
  const float gm = gamma[0];
  const int cl = tid >> 2, nc = (tid & 3) * 16;
  const size_t xo = (size_t)b * C_ * N_ + (size_t)(c0 + cl) * N_ + n0 + nc;
  const float* sp = fl + cl * 68 + nc;
#pragma unroll
  for (int k2 = 0; k2 < 4; ++k2) {
    float4 v = *(const float4*)(sp + k2 * 4);
    float4 xi = *(const float4*)(x + xo + k2 * 4);
    float4 r;
    r.x = gm * v.x + xi.x;
    r.y = gm * v.y + xi.y;
    r.z = gm * v.z + xi.z;
    r.w = gm * v.w + xi.w;
    *(float4*)(out + xo + k2 * 4) = r;
  }
}

// ============================ launch =======================================
extern "C" void kernel_launch(void* const* d_in, const int* in_sizes, int n_in,
                              void* d_out, int out_size, void* d_ws, size_t ws_size,
                              hipStream_t stream) {
  const float* x = (const float*)d_in[0];
  const float* wth = (const float*)d_in[1];
  const float* wph = (const float*)d_in[2];
  const float* wg = (const float*)d_in[3];
  const float* wo = (const float*)d_in[4];
  const float* gamma = (const float*)d_in[5];
  const float* pool = (const float*)d_in[6];
  float* out = (float*)d_out;

  char* ws = (char*)d_ws;
  u16* wcat    = (u16*)(ws + 0);          //  384*1024*2 = 786432
  u16* wo_bf   = (u16*)(ws + 786432);     // 1024*128*2  = 262144
  u16* pool_k  = (u16*)(ws + 1048576);    // 2048*128*2  = 524288
  u16* pool_vt = (u16*)(ws + 1572864);    //  32*128*64*2 = 524288
  u16* q_t     = (u16*)(ws + 2097152);    // 8*4096*128*2 = 8388608
  u16* k_t     = (u16*)(ws + 10485760);   // 8*4096*128*2 = 8388608
  u16* gvt     = (u16*)(ws + 18874368);   // 8*64*128*64*2 = 8388608
  u16* feat    = (u16*)(ws + 27262976);   // 8*4096*128*2 = 8388608

  prep_kernel<<<4096, 256, 0, stream>>>(wth, wph, wg, wo, pool, wcat, wo_bf, pool_k, pool_vt);
  proj_kernel<<<dim3(3, 256), 256, 0, stream>>>(x, wcat, q_t, k_t, gvt);
  attn_kernel<<<512, 256, 0, stream>>>(q_t, k_t, pool_k, pool_vt, gvt, feat);
  final_kernel<<<dim3(64, 16, 8), 256, 0, stream>>>(x, wo_bf, feat, gamma, out);
}